// Round 2
// baseline (209.757 us; speedup 1.0000x reference)
//
#include <hip/hip_runtime.h>
#include <math.h>

#define BB 8
#define SS 1024
#define EE 768
#define HH 12
#define DD 64
#define MM (BB*SS)   // 8192

typedef __attribute__((ext_vector_type(8))) short short8;   // 8 bf16 = 4 VGPRs
typedef __attribute__((ext_vector_type(4))) short short4v;  // 8 B
typedef __attribute__((ext_vector_type(4))) float f32x4;

// round-to-nearest-even fp32 -> bf16 bits (finite inputs only)
static __device__ __forceinline__ short f2bf(float x) {
    unsigned u = __float_as_uint(x);
    u += 0x7fffu + ((u >> 16) & 1u);
    return (short)(u >> 16);
}
// fast round-half-up (positive finite inputs; differs from RNE only on ties)
static __device__ __forceinline__ short f2bf_fast(float x) {
    return (short)((__float_as_uint(x) + 0x8000u) >> 16);
}

// async global->LDS, 16B per lane; LDS dest = wave-uniform base + lane*16
static __device__ __forceinline__ void gload_lds16(const void* g, void* l) {
    __builtin_amdgcn_global_load_lds((__attribute__((address_space(1))) void*)g,
                                     (__attribute__((address_space(3))) void*)l,
                                     16, 0, 0);
}

#define BAR __builtin_amdgcn_s_barrier()
#define VMW(n) asm volatile("s_waitcnt vmcnt(" #n ")" ::: "memory")

// ---------------------------------------------------------------------------
// cast X fp32 -> bf16
// ---------------------------------------------------------------------------
__global__ __launch_bounds__(256)
void cast_x(const float* __restrict__ src, short* __restrict__ dst) {
    const long i = ((long)blockIdx.x * 256 + threadIdx.x) * 4;
    float4 v = *(const float4*)&src[i];
    short4v o;
    o.x = f2bf(v.x); o.y = f2bf(v.y); o.z = f2bf(v.z); o.w = f2bf(v.w);
    *(short4v*)&dst[i] = o;
}

// ---------------------------------------------------------------------------
// transpose+cast the 4 weight matrices [768][768] fp32 -> Wt[z][N][K] bf16
// ---------------------------------------------------------------------------
__global__ __launch_bounds__(256)
void wcast_t(const float* __restrict__ W0, const float* __restrict__ W1,
             const float* __restrict__ W2, const float* __restrict__ W3,
             short* __restrict__ Wt) {
    __shared__ short T[64][72];
    const int z = blockIdx.z;
    const float* sp = (z == 0) ? W0 : (z == 1) ? W1 : (z == 2) ? W2 : W3;
    short* dp = Wt + (long)z * EE * EE;
    const int i0 = blockIdx.y * 64;
    const int j0 = blockIdx.x * 64;
    const int tid = threadIdx.x;
#pragma unroll
    for (int rep = 0; rep < 4; ++rep) {
        const int r = (tid >> 4) + rep * 16;
        const int c = (tid & 15) * 4;
        float4 v = *(const float4*)&sp[(long)(i0 + r) * EE + j0 + c];
        T[c + 0][r] = f2bf(v.x);
        T[c + 1][r] = f2bf(v.y);
        T[c + 2][r] = f2bf(v.z);
        T[c + 3][r] = f2bf(v.w);
    }
    __syncthreads();
#pragma unroll
    for (int rep = 0; rep < 4; ++rep) {
        const int rr = (tid >> 4) + rep * 16;
        const int cc = (tid & 15) * 4;
        short4v o;
        o.x = T[rr][cc + 0]; o.y = T[rr][cc + 1];
        o.z = T[rr][cc + 2]; o.w = T[rr][cc + 3];
        *(short4v*)&dp[(long)(j0 + rr) * EE + i0 + cc] = o;
    }
}

// ---------------------------------------------------------------------------
// bf16 MFMA GEMM core (m97 structure) — still used by gemm_proj.
// ---------------------------------------------------------------------------
#define GEMM_CORE(Abase, Bbase, row0, col0)                                     \
    f32x4 acc[4][4];                                                            \
    _Pragma("unroll") for (int i = 0; i < 4; ++i)                               \
        _Pragma("unroll") for (int j = 0; j < 4; ++j)                           \
            acc[i][j] = (f32x4){0.f, 0.f, 0.f, 0.f};                            \
    const int rm = (w & 1) * 64, cn = (w >> 1) * 64;                            \
    for (int k0 = 0; k0 < EE; k0 += 64) {                                       \
        __syncthreads();                                                        \
        _Pragma("unroll") for (int i = 0; i < 4; ++i) {                         \
            const int chunk = w * 256 + i * 64 + lane;                          \
            const int r = chunk >> 3;                                          \
            const int cs = (((chunk & 7) ^ (r & 7)) << 3);                      \
            short* ldsA = Al + (w * 256 + i * 64) * 8;                          \
            short* ldsB = Bl + (w * 256 + i * 64) * 8;                          \
            gload_lds16(&Abase[(long)(row0 + r) * EE + k0 + cs], ldsA);         \
            gload_lds16(&Bbase[(long)(col0 + r) * EE + k0 + cs], ldsB);         \
        }                                                                       \
        __syncthreads();                                                        \
        _Pragma("unroll") for (int ks = 0; ks < 2; ++ks) {                      \
            short8 af[4], bf[4];                                                \
            _Pragma("unroll") for (int t = 0; t < 4; ++t)                       \
                af[t] = *(const short8*)&Al[(rm + t * 16 + m) * 64 +            \
                                            (((ks * 4 + quad) ^ (m & 7)) << 3)]; \
            _Pragma("unroll") for (int t = 0; t < 4; ++t)                       \
                bf[t] = *(const short8*)&Bl[(cn + t * 16 + m) * 64 +            \
                                            (((ks * 4 + quad) ^ (m & 7)) << 3)]; \
            _Pragma("unroll") for (int mt = 0; mt < 4; ++mt)                    \
                _Pragma("unroll") for (int nt = 0; nt < 4; ++nt)                \
                    acc[mt][nt] = __builtin_amdgcn_mfma_f32_16x16x32_bf16(      \
                        af[mt], bf[nt], acc[mt][nt], 0, 0, 0);                  \
        }                                                                       \
    }

// Q pre-scale: 1/sqrt(D) * log2(e)  (exp done as 2^x in attention)
#define QSCALE 0.1803368801111204f

// ---------------------------------------------------------------------------
// Fused QKV — 256x256 8-phase schedule (T2+T3+T4+T5), BK=64, 512 thr / 8 waves
// (2M x 4N), per-wave C = 128x64 = acc[8][4]. LDS 128 KiB: Ae,Be,Ao,Bo slots
// (even/odd K-tiles, fixed parity -> uniform code, no buffer toggle).
//
// Stage/consume ledger (steady state, iter it computes K-tiles t=2it, t+1):
//   reads: p1 Ae(mt0-3)+Be(nt0-1), p2 Be(nt2-3), p3 Ae(mt4-7),
//          p5 Ao(mt0-3)+Bo(nt0-1), p6 Bo(nt2-3), p7 Ao(mt4-7)
//   -> Be consumed end-p2, Ae end-p3, Bo end-p6, Ao end-p7.
//   stages (2 gloads/thread each): s1 Ao.h0[t+1]@p1, s2 Ao.h1[t+1]@p2,
//     s3 Be.h0[t+2]@p3, s4 Be.h1[t+2]@p4, s5 Ae.h0[t+2]@p4, s6 Ae.h1[t+2]@p5,
//     s7 Bo.h0[t+3]@p7, s8 Bo.h1[t+3]@p8.
//   Every stage targets a region consumed >=1 phase earlier; two barriers per
//   phase make cross-wave WAR safe (reads complete before each wave's closing
//   barrier via compiler lgkmcnt before MFMA).
//   Waits (wait-THEN-barrier, so one wave's reads are safe vs OTHER waves'
//   in-flight gload_lds):  VMW(6) before p4's closing barrier (allows s3,s4,s5
//   = 6 newest; guarantees tile t+1 = s7,s8(prev)+s1,s2 for p5) and VMW(4)
//   before p8's closing barrier (allows s7,s8; guarantees tile t+2 for next p1).
//   Prologue stages tile0 (Ae,Be) then tile1 B (Bo) = 12 loads; VMW(4)+BAR.
//   Last iter stages clamp to tile 11 (harmless L2-hot re-reads).
// ---------------------------------------------------------------------------
#define QKV_STG(Ld, Gbase, gr0, k0)                                           \
    do {                                                                      \
        _Pragma("unroll") for (int j = 0; j < 2; ++j) {                       \
            const int chunk = j * 512 + tid;                                  \
            const int r = chunk >> 3;                                         \
            const int cs = ((chunk & 7) ^ (r & 7)) << 3;                      \
            gload_lds16(&(Gbase)[(long)((gr0) + r) * EE + (k0) + cs],         \
                        (Ld) + (j * 512 + w * 64) * 8);                       \
        }                                                                     \
    } while (0)

#define QKV_RDA(Ld, mb)                                                       \
    _Pragma("unroll") for (int t = 0; t < 4; ++t)                             \
        _Pragma("unroll") for (int ks = 0; ks < 2; ++ks)                      \
            af[t][ks] = *(const short8*)&(Ld)[(wr * 128 + ((mb) + t) * 16 + m) * 64 + \
                                              (((ks * 4 + quad) ^ (m & 7)) << 3)];

#define QKV_RDB(Ld, dst, nb)                                                  \
    _Pragma("unroll") for (int t = 0; t < 2; ++t)                             \
        _Pragma("unroll") for (int ks = 0; ks < 2; ++ks)                      \
            dst[t][ks] = *(const short8*)&(Ld)[(wc * 64 + ((nb) + t) * 16 + m) * 64 + \
                                               (((ks * 4 + quad) ^ (m & 7)) << 3)];

#define QKV_MF(mb, bfx, nb)                                                   \
    __builtin_amdgcn_s_setprio(1);                                            \
    _Pragma("unroll") for (int mq = 0; mq < 4; ++mq)                          \
        _Pragma("unroll") for (int nq = 0; nq < 2; ++nq)                      \
            _Pragma("unroll") for (int ks = 0; ks < 2; ++ks)                  \
                acc[(mb) + mq][(nb) + nq] = __builtin_amdgcn_mfma_f32_16x16x32_bf16( \
                    af[mq][ks], bfx[nq][ks], acc[(mb) + mq][(nb) + nq], 0, 0, 0); \
    __builtin_amdgcn_s_setprio(0);

__global__ __launch_bounds__(512, 2)
void gemm_qkv(const short* __restrict__ Xb, const short* __restrict__ Wt,
              const float* __restrict__ bq, const float* __restrict__ bk,
              const float* __restrict__ bv,
              short* __restrict__ Qb, short* __restrict__ Kb,
              short* __restrict__ Vb) {
    __shared__ short SMEM[65536];            // 128 KiB
    short* const Ae = SMEM;                  // 256x64 bf16 (even K-tile A)
    short* const Be = SMEM + 16384;          // even K-tile B
    short* const Ao = SMEM + 32768;          // odd  K-tile A
    short* const Bo = SMEM + 49152;          // odd  K-tile B

    const int tid = threadIdx.x;
    const int w = tid >> 6, lane = tid & 63;
    const int m = lane & 15, quad = lane >> 4;
    const int wr = w >> 2, wc = w & 3;       // 2M x 4N wave grid

    // XCD-aware bijective swizzle: 288 = 8 XCD x 36 (4 row-tiles x 9 cols)
    const int flat = blockIdx.x + 9 * blockIdx.y;       // 0..287
    const int id   = (flat & 7) * 36 + (flat >> 3);
    const int lcl  = id % 36;
    const int rt   = (id / 36) * 4 + (lcl & 3);         // 0..31
    const int ct   = lcl >> 2;                          // 0..8
    const int row0 = rt * 256;
    const int col0 = ct * 256;
    const int wsel = col0 / 768;
    const int col0w = col0 % 768;
    const short* Wsel = Wt + (long)wsel * EE * EE;
    const float* bias = (wsel == 0) ? bq : (wsel == 1) ? bk : bv;

    f32x4 acc[8][4];
#pragma unroll
    for (int i = 0; i < 8; ++i)
#pragma unroll
        for (int j = 0; j < 4; ++j) acc[i][j] = (f32x4){0.f, 0.f, 0.f, 0.f};

    // ---- prologue: tile0 full + tile1 B; wait own 8 oldest, then barrier ----
    QKV_STG(Ae + 0,    Xb,   row0 + 0,   0);
    QKV_STG(Ae + 8192, Xb,   row0 + 128, 0);
    QKV_STG(Be + 0,    Wsel, col0w + 0,   0);
    QKV_STG(Be + 8192, Wsel, col0w + 128, 0);
    QKV_STG(Bo + 0,    Wsel, col0w + 0,   64);
    QKV_STG(Bo + 8192, Wsel, col0w + 128, 64);
    VMW(4);
    BAR;

#pragma unroll 1
    for (int it = 0; it < 6; ++it) {
        const int kA = (2 * it + 1) * 64;               // tile 2it+1 (<=11, valid)
        const int t2 = 2 * it + 2, t3 = 2 * it + 3;
        const int k2 = (t2 < 12 ? t2 : 11) * 64;        // clamp: L2-hot re-read
        const int k3 = (t3 < 12 ? t3 : 11) * 64;
        short8 af[4][2], bf01[2][2], bf23[2][2];
        // -- phase 1: Q0 (mt0-3 x nt0-1) on even tile --
        QKV_RDA(Ae, 0);
        QKV_RDB(Be, bf01, 0);
        QKV_STG(Ao + 0, Xb, row0 + 0, kA);              // s1
        BAR;
        QKV_MF(0, bf01, 0);
        BAR;
        // -- phase 2: Q1 (mt0-3 x nt2-3) --
        QKV_RDB(Be, bf23, 2);
        QKV_STG(Ao + 8192, Xb, row0 + 128, kA);         // s2
        BAR;
        QKV_MF(0, bf23, 2);
        BAR;
        // -- phase 3: Q2 (mt4-7 x nt0-1) --
        QKV_RDA(Ae, 4);
        QKV_STG(Be + 0, Wsel, col0w + 0, k2);           // s3
        BAR;
        QKV_MF(4, bf01, 0);
        BAR;
        // -- phase 4: Q3 (mt4-7 x nt2-3) --
        QKV_STG(Be + 8192, Wsel, col0w + 128, k2);      // s4
        QKV_STG(Ae + 0,    Xb,   row0 + 0,   k2);       // s5
        BAR;
        QKV_MF(4, bf23, 2);
        VMW(6);                                         // tile 2it+1 ready
        BAR;
        // -- phase 5: Q0 on odd tile --
        QKV_RDA(Ao, 0);
        QKV_RDB(Bo, bf01, 0);
        QKV_STG(Ae + 8192, Xb, row0 + 128, k2);         // s6
        BAR;
        QKV_MF(0, bf01, 0);
        BAR;
        // -- phase 6 --
        QKV_RDB(Bo, bf23, 2);
        BAR;
        QKV_MF(0, bf23, 2);
        BAR;
        // -- phase 7 --
        QKV_RDA(Ao, 4);
        QKV_STG(Bo + 0, Wsel, col0w + 0, k3);           // s7
        BAR;
        QKV_MF(4, bf01, 0);
        BAR;
        // -- phase 8 --
        QKV_STG(Bo + 8192, Wsel, col0w + 128, k3);      // s8
        BAR;
        QKV_MF(4, bf23, 2);
        VMW(4);                                         // tile 2it+2 ready
        BAR;
    }

    // ---- epilogue: drain garbage stages, reuse LDS in two half passes ----
    VMW(0);
    __syncthreads();
    const int b = row0 >> 10, s0 = row0 & 1023;
    short* EP = SMEM;

    if (wsel < 2) {
        // Q/K -> [B,H,S,D]; EP as [128][264]
        const float scale = (wsel == 0) ? QSCALE : 1.0f;
        short* QK = (wsel == 0) ? Qb : Kb;
#pragma unroll 1
        for (int hh = 0; hh < 2; ++hh) {
            if (wr == hh) {
#pragma unroll
                for (int nt = 0; nt < 4; ++nt) {
                    const float bvv = bias[col0w + wc * 64 + nt * 16 + m];
#pragma unroll
                    for (int mt = 0; mt < 8; ++mt)
#pragma unroll
                        for (int r = 0; r < 4; ++r)
                            EP[(mt * 16 + quad * 4 + r) * 264 + wc * 64 + nt * 16 + m] =
                                f2bf((acc[mt][nt][r] + bvv) * scale);
                }
            }
            __syncthreads();
#pragma unroll
            for (int rep = 0; rep < 8; ++rep) {
                const int chunk = tid + rep * 512;      // 0..4095
                const int row = chunk >> 5;             // 0..127
                const int cc = (chunk & 31) * 8;        // 0..248
                const int colg = col0w + cc;
                const int h = colg >> 6, d = colg & 63;
                short8 v = *(const short8*)&EP[row * 264 + cc];
                *(short8*)&QK[((long)(b * HH + h) * SS + s0 + hh * 128 + row) * DD + d] = v;
            }
            __syncthreads();
        }
    } else {
        // V -> [B,H,D,S]; EP transposed as [256][132]
#pragma unroll 1
        for (int hh = 0; hh < 2; ++hh) {
            if (wr == hh) {
#pragma unroll
                for (int nt = 0; nt < 4; ++nt) {
                    const float bvv = bias[col0w + wc * 64 + nt * 16 + m];
#pragma unroll
                    for (int mt = 0; mt < 8; ++mt) {
                        short4v o;
                        o.x = f2bf(acc[mt][nt][0] + bvv);
                        o.y = f2bf(acc[mt][nt][1] + bvv);
                        o.z = f2bf(acc[mt][nt][2] + bvv);
                        o.w = f2bf(acc[mt][nt][3] + bvv);
                        *(short4v*)&EP[(wc * 64 + nt * 16 + m) * 132 + mt * 16 + quad * 4] = o;
                    }
                }
            }
            __syncthreads();
#pragma unroll
            for (int rep = 0; rep < 8; ++rep) {
                const int chunk = tid + rep * 512;      // 0..4095
                const int col = chunk >> 4;             // 0..255
                const int sc8 = (chunk & 15) * 8;       // 0..120
                const int colg = col0w + col;
                const int h = colg >> 6, d = colg & 63;
                short8 v = *(const short8*)&EP[col * 132 + sc8];
                *(short8*)&Vb[((long)(b * HH + h) * DD + d) * SS + s0 + hh * 128 + sc8] = v;
            }
            __syncthreads();
        }
    }
}

// Output projection: Cb bf16 [M][E] @ WoT + bo -> fp32 d_out. 384 blocks,
// XCD chunk = 8 row-tiles x 6 cols.
__global__ __launch_bounds__(256)
void gemm_proj(const short* __restrict__ Cb, const short* __restrict__ WoT,
               const float* __restrict__ bo, float* __restrict__ out) {
    __shared__ short Al[128 * 64];
    __shared__ short Bl[128 * 64];
    const int tid = threadIdx.x, w = tid >> 6, lane = tid & 63;
    const int m = lane & 15, quad = lane >> 4;

    const int flat = blockIdx.x + 6 * blockIdx.y;       // 0..383
    const int id   = (flat & 7) * 48 + (flat >> 3);
    const int xcd  = id / 48;
    const int lcl  = id % 48;
    const int row0 = (xcd * 8 + (lcl & 7)) * 128;
    const int col0 = (lcl >> 3) * 128;

    GEMM_CORE(Cb, WoT, row0, col0)

#pragma unroll
    for (int nt = 0; nt < 4; ++nt) {
        const int colg = col0 + cn + nt * 16 + m;
        const float bvv = bo[colg];
#pragma unroll
        for (int mt = 0; mt < 4; ++mt)
#pragma unroll
            for (int r = 0; r < 4; ++r) {
                const int srow = row0 + rm + mt * 16 + quad * 4 + r;
                out[(long)srow * EE + colg] = acc[mt][nt][r] + bvv;
            }
    }
}

// ---------------------------------------------------------------------------
// Flash attention, bf16 MFMA 16x16x32 (round-1 version: gload_lds staging,
// double-buffered prefetch, setprio, XCD swizzle).
// ---------------------------------------------------------------------------
#define ATTN_STAGE(Kdst, Vdst, k0)                                            \
    do {                                                                      \
        _Pragma("unroll") for (int i = 0; i < 2; ++i) {                       \
            const int chunk = w * 128 + i * 64 + l;                           \
            const int r = chunk >> 3;                                         \
            const int cs = ((chunk & 7) ^ (r & 7)) << 3;                      \
            gload_lds16(&Kg[(long)((k0) + r) * DD + cs],                      \
                        (Kdst) + (w * 128 + i * 64) * 8);                     \
            gload_lds16(&Vg[(long)r * SS + (k0) + cs],                        \
                        (Vdst) + (w * 128 + i * 64) * 8);                     \
        }                                                                     \
    } while (0)

#define ATTN_COMPUTE(Kbuf, Vbuf)                                              \
    do {                                                                      \
        f32x4 sc[2][4];                                                       \
        __builtin_amdgcn_s_setprio(1);                                        \
        _Pragma("unroll") for (int nt = 0; nt < 4; ++nt) {                    \
            const short* kb = (Kbuf) + (nt * 16 + m) * 64;                    \
            short8 b0 = *(const short8*)&kb[(quad ^ (m & 7)) << 3];           \
            short8 b1 = *(const short8*)&kb[((4 + quad) ^ (m & 7)) << 3];     \
            _Pragma("unroll") for (int g = 0; g < 2; ++g) {                   \
                f32x4 a = (f32x4){0.f, 0.f, 0.f, 0.f};                        \
                a = __builtin_amdgcn_mfma_f32_16x16x32_bf16(aq[g][0], b0, a, 0, 0, 0); \
                a = __builtin_amdgcn_mfma_f32_16x16x32_bf16(aq[g][1], b1, a, 0, 0, 0); \
                sc[g][nt] = a;                                                \
            }                                                                 \
        }                                                                     \
        __builtin_amdgcn_s_setprio(0);                                        \
        _Pragma("unroll") for (int g = 0; g < 2; ++g)                         \
            _Pragma("unroll") for (int nt = 0; nt < 4; ++nt)                  \
                _Pragma("unroll") for (int r = 0; r < 4; ++r)                 \
                    sc[g][nt][r] = __builtin_amdgcn_exp2f(sc[g][nt][r]);      \
        short* Pw = Pl + w * 32 * 72;                                         \
        _Pragma("unroll") for (int g = 0; g < 2; ++g)                         \
            _Pragma("unroll") for (int nt = 0; nt < 4; ++nt)                  \
                _Pragma("unroll") for (int r = 0; r < 4; ++r)                 \
                    Pw[(g * 16 + quad * 4 + r) * 72 + nt * 16 + m] =          \
                        f2bf_fast(sc[g][nt][r]);                              \
        short8 ap[2][2];                                                      \
        _Pragma("unroll") for (int g = 0; g < 2; ++g) {                       \
            ap[g][0] = *(const short8*)(Pw + (g * 16 + m) * 72 + quad * 8);   \
            ap[g][1] = *(const short8*)(Pw + (g * 16 + m) * 72 + 32 + quad * 8); \
        }                                                                     \
        __builtin_amdgcn_s_setprio(1);                                        \
        _Pragma("unroll") for (int g = 0; g < 2; ++g) {                       \
            lacc[g] = __builtin_amdgcn_mfma_f32_16x16x32_bf16(ap[g][0], ones, lacc[g], 0, 0, 0); \
            lacc[g] = __builtin_amdgcn_mfma_f32_16x16x32_bf16(ap[g][1], ones, lacc[g], 0, 0, 0); \
        }                                                                     \
        _Pragma("unroll") for (int dt = 0; dt < 4; ++dt) {                    \
            const short* vb = (Vbuf) + (dt * 16 + m) * 64;                    \
            short8 b0 = *(const short8*)&vb[(quad ^ (m & 7)) << 3];           \
            short8 b1 = *(const short8*)&vb[((4 + quad) ^ (m & 7)) << 3];     \
            _Pragma("unroll") for (int g = 0; g < 2; ++g) {                   \
                O[g][dt] = __builtin_amdgcn_mfma_f32_16x16x32_bf16(ap[g][0], b0, O[g][dt], 0, 0, 0); \
                O[g][dt] = __builtin_amdgcn_mfma_f32_16x16x32_bf16(ap[g][1], b1, O[g][dt], 0, 0, 0); \
            }                                                                 \
        }                                                                     \
        __builtin_amdgcn_s_setprio(0);                                        \
    } while (0)

__global__ __launch_bounds__(256)
void attn_mfma(const short* __restrict__ Q,
               const short* __restrict__ K,
               const short* __restrict__ Vt,
               short* __restrict__ out) {
    __shared__ short K0l[64 * 64];
    __shared__ short K1l[64 * 64];
    __shared__ short V0l[64 * 64];
    __shared__ short V1l[64 * 64];
    __shared__ short Pl[4 * 32 * 72];

    const int tid  = threadIdx.x;
    const int w    = tid >> 6;
    const int l    = tid & 63;
    const int m    = l & 15;
    const int quad = l >> 4;

    const int flat = blockIdx.x + 8 * blockIdx.y + 96 * blockIdx.z;  // 0..767
    const int id   = (flat & 7) * 96 + (flat >> 3);
    const int qt   = id & 7;
    const int bh   = id >> 3;            // 0..95
    const int b    = bh / HH;
    const int h    = bh % HH;
    const int q0   = qt * 128;

    const short* Qg = Q  + (long)bh * SS * DD;
    const short* Kg = K  + (long)bh * SS * DD;
    const short* Vg = Vt + (long)bh * DD * SS;

    short8 aq[2][2];
#pragma unroll
    for (int g = 0; g < 2; ++g) {
        const int row = q0 + w * 32 + g * 16 + m;
        aq[g][0] = *(const short8*)(Qg + (long)row * DD + quad * 8);
        aq[g][1] = *(const short8*)(Qg + (long)row * DD + 32 + quad * 8);
    }

    short8 ones;
#pragma unroll
    for (int i = 0; i < 8; ++i) ones[i] = (short)0x3F80;

    f32x4 O[2][4], lacc[2];
#pragma unroll
    for (int g = 0; g < 2; ++g) {
        lacc[g] = (f32x4){0.f, 0.f, 0.f, 0.f};
#pragma unroll
        for (int dt = 0; dt < 4; ++dt) O[g][dt] = (f32x4){0.f, 0.f, 0.f, 0.f};
    }

    ATTN_STAGE(K0l, V0l, 0);
    __syncthreads();

#pragma unroll 1
    for (int kt2 = 0; kt2 < 8; ++kt2) {
        const int k0 = kt2 * 128;
        ATTN_STAGE(K1l, V1l, k0 + 64);
        ATTN_COMPUTE(K0l, V0l);
        __syncthreads();
        if (kt2 < 7) ATTN_STAGE(K0l, V0l, k0 + 128);
        ATTN_COMPUTE(K1l, V1l);
        __syncthreads();
    }

#pragma unroll
    for (int g = 0; g < 2; ++g)
#pragma unroll
        for (int r = 0; r < 4; ++r) {
            const float inv = 1.0f / lacc[g][r];
            const int qo = q0 + w * 32 + g * 16 + quad * 4 + r;
            short* orow = out + ((long)(b * SS + qo)) * EE + h * DD;
#pragma unroll
            for (int dt = 0; dt < 4; ++dt)
                orow[dt * 16 + m] = f2bf(O[g][dt][r] * inv);
        }
}

// ---------------------------------------------------------------------------
extern "C" void kernel_launch(void* const* d_in, const int* in_sizes, int n_in,
                              void* d_out, int out_size, void* d_ws, size_t ws_size,
                              hipStream_t stream) {
    const float* X  = (const float*)d_in[0];
    const float* Wq = (const float*)d_in[1];
    const float* bq = (const float*)d_in[2];
    const float* Wk = (const float*)d_in[3];
    const float* bk = (const float*)d_in[4];
    const float* Wv = (const float*)d_in[5];
    const float* bv = (const float*)d_in[6];
    const float* Wo = (const float*)d_in[7];
    const float* bo = (const float*)d_in[8];

    const long SEG = (long)BB * HH * SS * DD;     // 6,291,456 elements
    const long WSEG = (long)EE * EE;              // 589,824
    short* Xb = (short*)d_ws;                     // [M][E] bf16
    short* Wt = Xb + SEG;                         // [4][E][E] bf16, N-major
    short* Qb = Wt + 4 * WSEG;                    // [B,H,S,D] bf16, pre-scaled
    short* Kb = Qb + SEG;                         // [B,H,S,D] bf16
    short* Vb = Kb + SEG;                         // [B,H,D,S] bf16
    short* Cb = Vb + SEG;                         // [M][E] bf16 concat

    cast_x<<<dim3(MM * EE / 4 / 256), 256, 0, stream>>>(X, Xb);
    wcast_t<<<dim3(12, 12, 4), 256, 0, stream>>>(Wq, Wk, Wv, Wo, Wt);

    gemm_qkv<<<dim3(9, 32), 512, 0, stream>>>(Xb, Wt, bq, bk, bv, Qb, Kb, Vb);

    attn_mfma<<<dim3(SS / 128, HH, BB), 256, 0, stream>>>(Qb, Kb, Vb, Cb);

    gemm_proj<<<dim3(6, 64), 256, 0, stream>>>(Cb, Wt + 3 * WSEG, bo,
                                               (float*)d_out);
}

// Round 3
// 200.600 us; speedup vs baseline: 1.0456x; 1.0456x over previous
//
#include <hip/hip_runtime.h>
#include <math.h>

#define BB 8
#define SS 1024
#define EE 768
#define HH 12
#define DD 64
#define MM (BB*SS)   // 8192

typedef __attribute__((ext_vector_type(8))) short short8;   // 8 bf16 = 4 VGPRs
typedef __attribute__((ext_vector_type(4))) short short4v;  // 8 B
typedef __attribute__((ext_vector_type(4))) float f32x4;

// round-to-nearest-even fp32 -> bf16 bits (finite inputs only)
static __device__ __forceinline__ short f2bf(float x) {
    unsigned u = __float_as_uint(x);
    u += 0x7fffu + ((u >> 16) & 1u);
    return (short)(u >> 16);
}
// fast round-half-up (positive finite inputs; differs from RNE only on ties)
static __device__ __forceinline__ short f2bf_fast(float x) {
    return (short)((__float_as_uint(x) + 0x8000u) >> 16);
}

// async global->LDS, 16B per lane; LDS dest = wave-uniform base + lane*16
static __device__ __forceinline__ void gload_lds16(const void* g, void* l) {
    __builtin_amdgcn_global_load_lds((__attribute__((address_space(1))) void*)g,
                                     (__attribute__((address_space(3))) void*)l,
                                     16, 0, 0);
}

#define BAR __builtin_amdgcn_s_barrier()
#define VMW(n) asm volatile("s_waitcnt vmcnt(" #n ")" ::: "memory")

// ---------------------------------------------------------------------------
// cast X fp32 -> bf16
// ---------------------------------------------------------------------------
__global__ __launch_bounds__(256)
void cast_x(const float* __restrict__ src, short* __restrict__ dst) {
    const long i = ((long)blockIdx.x * 256 + threadIdx.x) * 4;
    float4 v = *(const float4*)&src[i];
    short4v o;
    o.x = f2bf(v.x); o.y = f2bf(v.y); o.z = f2bf(v.z); o.w = f2bf(v.w);
    *(short4v*)&dst[i] = o;
}

// ---------------------------------------------------------------------------
// transpose+cast the 4 weight matrices [768][768] fp32 -> Wt[z][N][K] bf16
// ---------------------------------------------------------------------------
__global__ __launch_bounds__(256)
void wcast_t(const float* __restrict__ W0, const float* __restrict__ W1,
             const float* __restrict__ W2, const float* __restrict__ W3,
             short* __restrict__ Wt) {
    __shared__ short T[64][72];
    const int z = blockIdx.z;
    const float* sp = (z == 0) ? W0 : (z == 1) ? W1 : (z == 2) ? W2 : W3;
    short* dp = Wt + (long)z * EE * EE;
    const int i0 = blockIdx.y * 64;
    const int j0 = blockIdx.x * 64;
    const int tid = threadIdx.x;
#pragma unroll
    for (int rep = 0; rep < 4; ++rep) {
        const int r = (tid >> 4) + rep * 16;
        const int c = (tid & 15) * 4;
        float4 v = *(const float4*)&sp[(long)(i0 + r) * EE + j0 + c];
        T[c + 0][r] = f2bf(v.x);
        T[c + 1][r] = f2bf(v.y);
        T[c + 2][r] = f2bf(v.z);
        T[c + 3][r] = f2bf(v.w);
    }
    __syncthreads();
#pragma unroll
    for (int rep = 0; rep < 4; ++rep) {
        const int rr = (tid >> 4) + rep * 16;
        const int cc = (tid & 15) * 4;
        short4v o;
        o.x = T[rr][cc + 0]; o.y = T[rr][cc + 1];
        o.z = T[rr][cc + 2]; o.w = T[rr][cc + 3];
        *(short4v*)&dp[(long)(j0 + rr) * EE + i0 + cc] = o;
    }
}

// ---------------------------------------------------------------------------
// bf16 MFMA GEMM core (m97 structure) — still used by gemm_proj.
// ---------------------------------------------------------------------------
#define GEMM_CORE(Abase, Bbase, row0, col0)                                     \
    f32x4 acc[4][4];                                                            \
    _Pragma("unroll") for (int i = 0; i < 4; ++i)                               \
        _Pragma("unroll") for (int j = 0; j < 4; ++j)                           \
            acc[i][j] = (f32x4){0.f, 0.f, 0.f, 0.f};                            \
    const int rm = (w & 1) * 64, cn = (w >> 1) * 64;                            \
    for (int k0 = 0; k0 < EE; k0 += 64) {                                       \
        __syncthreads();                                                        \
        _Pragma("unroll") for (int i = 0; i < 4; ++i) {                         \
            const int chunk = w * 256 + i * 64 + lane;                          \
            const int r = chunk >> 3;                                          \
            const int cs = (((chunk & 7) ^ (r & 7)) << 3);                      \
            short* ldsA = Al + (w * 256 + i * 64) * 8;                          \
            short* ldsB = Bl + (w * 256 + i * 64) * 8;                          \
            gload_lds16(&Abase[(long)(row0 + r) * EE + k0 + cs], ldsA);         \
            gload_lds16(&Bbase[(long)(col0 + r) * EE + k0 + cs], ldsB);         \
        }                                                                       \
        __syncthreads();                                                        \
        _Pragma("unroll") for (int ks = 0; ks < 2; ++ks) {                      \
            short8 af[4], bf[4];                                                \
            _Pragma("unroll") for (int t = 0; t < 4; ++t)                       \
                af[t] = *(const short8*)&Al[(rm + t * 16 + m) * 64 +            \
                                            (((ks * 4 + quad) ^ (m & 7)) << 3)]; \
            _Pragma("unroll") for (int t = 0; t < 4; ++t)                       \
                bf[t] = *(const short8*)&Bl[(cn + t * 16 + m) * 64 +            \
                                            (((ks * 4 + quad) ^ (m & 7)) << 3)]; \
            _Pragma("unroll") for (int mt = 0; mt < 4; ++mt)                    \
                _Pragma("unroll") for (int nt = 0; nt < 4; ++nt)                \
                    acc[mt][nt] = __builtin_amdgcn_mfma_f32_16x16x32_bf16(      \
                        af[mt], bf[nt], acc[mt][nt], 0, 0, 0);                  \
        }                                                                       \
    }

// Q pre-scale: 1/sqrt(D) * log2(e)  (exp done as 2^x in attention)
#define QSCALE 0.1803368801111204f

// ---------------------------------------------------------------------------
// Fused QKV — 256x128 tile, BK=64, 512 thr / 8 waves (2M x 4N), per-wave
// C = 128x32 = acc[8][2]. 4-phase counted-vmcnt pipeline (T2+T4+T5).
// Grid 32x18 = 576 blocks -> max CU load 3, avg 2.25 (75% tail eff vs the
// round-2 256² grid's 56%). LDS 96 KiB: Ae/Ao 32K + Be/Bo 16K.
//
// Stage ledger (iter it computes tiles t=2it even-buf, t+1 odd-buf):
//   reads: p1 Ae.q0q2+Be(all), p2 Ae.q1q3, p3 Ao.q0q2+Bo(all), p4 Ao.q1q3
//   frees: Be after p1, Ae.q0q2 after p1, Ae.q1q3 after p2, Bo+Ao.q0q2
//          after p3, Ao.q1q3 after p4.
//   stages (1 gload/thread each; A tile = 4 quarters, B tile = 2 halves):
//     p1: Ao[t+1].q1q3 (2)   -> read this iter p4   (3-phase gap)
//     p2: Be[t+2] h0h1 + Ae[t+2].q0q2 (4) -> read next p1 (3-phase gap)
//     p3: Ae[t+2].q1q3 (2)   -> read next p2        (3-phase gap)
//     p4: Bo[t+3] h0h1 + Ao[t+3].q0q2 (4) -> read next p3 (3-phase gap)
//   Outstanding-count simulation gives a UNIFORM vmcnt(6) before every
//   phase-closing barrier: each wait drains exactly the group consumed in
//   the following phase (p1-wait drains prev p3's 2, p2-wait drains prev
//   p4's 4, p3-wait drains p1's 2, p4-wait drains p2's 4). Wait-then-
//   barrier makes one wave's reads safe vs other waves' in-flight gloads.
//   Prologue: 10 loads in chain order (Ae.q0q2,Be | Ae.q1q3 | Bo1,Ao1.q0q2),
//   VMW(6) -> first 4 drained, chain state identical to steady state.
//   Last iter stages clamp to tile 11 (harmless L2-hot re-reads).
// ---------------------------------------------------------------------------
#define STG1(Ld, Gbase, gr0, k0)                                              \
    do {                                                                      \
        const int r_ = tid >> 3;                                              \
        const int cs_ = ((tid & 7) ^ (r_ & 7)) << 3;                          \
        gload_lds16(&(Gbase)[(long)((gr0) + r_) * EE + (k0) + cs_],           \
                    (Ld) + w * 512);                                          \
    } while (0)

#define QKV_RDA(Ld, mb)                                                       \
    _Pragma("unroll") for (int t = 0; t < 4; ++t)                             \
        _Pragma("unroll") for (int ks = 0; ks < 2; ++ks)                      \
            af[t][ks] = *(const short8*)&(Ld)[(wr * 128 + ((mb) + t) * 16 + m) * 64 + \
                                              (((ks * 4 + quad) ^ (m & 7)) << 3)];

#define QKV_RDB(Ld)                                                           \
    _Pragma("unroll") for (int t = 0; t < 2; ++t)                             \
        _Pragma("unroll") for (int ks = 0; ks < 2; ++ks)                      \
            bf[t][ks] = *(const short8*)&(Ld)[(wc * 32 + t * 16 + m) * 64 +   \
                                              (((ks * 4 + quad) ^ (m & 7)) << 3)];

#define QKV_MF(mb)                                                            \
    __builtin_amdgcn_s_setprio(1);                                            \
    _Pragma("unroll") for (int mq = 0; mq < 4; ++mq)                          \
        _Pragma("unroll") for (int nq = 0; nq < 2; ++nq)                      \
            _Pragma("unroll") for (int ks = 0; ks < 2; ++ks)                  \
                acc[(mb) + mq][nq] = __builtin_amdgcn_mfma_f32_16x16x32_bf16( \
                    af[mq][ks], bf[nq][ks], acc[(mb) + mq][nq], 0, 0, 0);     \
    __builtin_amdgcn_s_setprio(0);

__global__ __launch_bounds__(512, 2)
void gemm_qkv(const short* __restrict__ Xb, const short* __restrict__ Wt,
              const float* __restrict__ bq, const float* __restrict__ bk,
              const float* __restrict__ bv,
              short* __restrict__ Qb, short* __restrict__ Kb,
              short* __restrict__ Vb) {
    __shared__ short SMEM[49152];            // 96 KiB
    short* const Ae = SMEM;                  // 256x64 bf16 even-tile A
    short* const Ao = SMEM + 16384;          // odd-tile A
    short* const Be = SMEM + 32768;          // 128x64 bf16 even-tile B
    short* const Bo = SMEM + 40960;          // odd-tile B

    const int tid = threadIdx.x;
    const int w = tid >> 6;
    const int m = tid & 15, quad = (tid & 63) >> 4;
    const int wr = w >> 2, wc = w & 3;       // 2M x 4N wave grid

    // XCD-aware bijective swizzle: 576 = 8 XCD x 72 (4 row-tiles x 18 cols,
    // rt fastest -> resident ~32 blocks/XCD span 4rt x 8ct: A 1.5MB + B 1.5MB
    // fits the 4 MiB XCD L2)
    const int flat = blockIdx.x + 18 * blockIdx.y;      // 0..575
    const int id   = (flat & 7) * 72 + (flat >> 3);
    const int lcl  = id % 72;
    const int rt   = (id / 72) * 4 + (lcl & 3);         // 0..31
    const int ct   = lcl >> 2;                          // 0..17
    const int row0 = rt * 256;
    const int wsel = ct / 6;
    const int col0w = (ct % 6) * 128;
    const short* Wsel = Wt + (long)wsel * EE * EE;
    const float* bias = (wsel == 0) ? bq : (wsel == 1) ? bk : bv;

    f32x4 acc[8][2];
#pragma unroll
    for (int i = 0; i < 8; ++i)
#pragma unroll
        for (int j = 0; j < 2; ++j) acc[i][j] = (f32x4){0.f, 0.f, 0.f, 0.f};

    // ---- prologue: chain-compatible order, 10 loads ----
    STG1(Ae + 0,     Xb,   row0 + 0,    0);
    STG1(Ae + 8192,  Xb,   row0 + 128,  0);
    STG1(Be + 0,     Wsel, col0w + 0,   0);
    STG1(Be + 4096,  Wsel, col0w + 64,  0);
    STG1(Ae + 4096,  Xb,   row0 + 64,   0);
    STG1(Ae + 12288, Xb,   row0 + 192,  0);
    STG1(Bo + 0,     Wsel, col0w + 0,   64);
    STG1(Bo + 4096,  Wsel, col0w + 64,  64);
    STG1(Ao + 0,     Xb,   row0 + 0,    64);
    STG1(Ao + 8192,  Xb,   row0 + 128,  64);
    VMW(6);
    BAR;

#pragma unroll 1
    for (int it = 0; it < 6; ++it) {
        const int kO1 = (2 * it + 1) * 64;              // <= 704, always valid
        const int t2 = 2 * it + 2, t3 = 2 * it + 3;
        const int kE2 = (t2 < 12 ? t2 : 11) * 64;       // clamp: hot re-read
        const int kO3 = (t3 < 12 ? t3 : 11) * 64;
        short8 af[4][2], bf[2][2];
        // -- phase 1: even tile, M-half 0 --
        QKV_RDA(Ae, 0);
        QKV_RDB(Be);
        STG1(Ao + 4096,  Xb, row0 + 64,  kO1);
        STG1(Ao + 12288, Xb, row0 + 192, kO1);
        BAR;
        QKV_MF(0);
        VMW(6);
        BAR;
        // -- phase 2: even tile, M-half 1 (B-frags live in regs) --
        QKV_RDA(Ae, 4);
        STG1(Be + 0,     Wsel, col0w + 0,  kE2);
        STG1(Be + 4096,  Wsel, col0w + 64, kE2);
        STG1(Ae + 0,     Xb,   row0 + 0,   kE2);
        STG1(Ae + 8192,  Xb,   row0 + 128, kE2);
        BAR;
        QKV_MF(4);
        VMW(6);
        BAR;
        // -- phase 3: odd tile, M-half 0 --
        QKV_RDA(Ao, 0);
        QKV_RDB(Bo);
        STG1(Ae + 4096,  Xb, row0 + 64,  kE2);
        STG1(Ae + 12288, Xb, row0 + 192, kE2);
        BAR;
        QKV_MF(0);
        VMW(6);
        BAR;
        // -- phase 4: odd tile, M-half 1 --
        QKV_RDA(Ao, 4);
        STG1(Bo + 0,     Wsel, col0w + 0,  kO3);
        STG1(Bo + 4096,  Wsel, col0w + 64, kO3);
        STG1(Ao + 0,     Xb,   row0 + 0,   kO3);
        STG1(Ao + 8192,  Xb,   row0 + 128, kO3);
        BAR;
        QKV_MF(4);
        VMW(6);
        BAR;
    }

    // ---- epilogue: drain garbage stages, single-pass LDS (tile fits) ----
    VMW(0);
    __syncthreads();
    const int b = row0 >> 10, s0 = row0 & 1023;
    short* EP = SMEM;

    if (wsel < 2) {
        // Q/K -> [B,H,S,D]; EP as [256][136]
        const float scale = (wsel == 0) ? QSCALE : 1.0f;
        short* QK = (wsel == 0) ? Qb : Kb;
#pragma unroll
        for (int nt = 0; nt < 2; ++nt) {
            const float bvv = bias[col0w + wc * 32 + nt * 16 + m];
#pragma unroll
            for (int mt = 0; mt < 8; ++mt)
#pragma unroll
                for (int r = 0; r < 4; ++r)
                    EP[(wr * 128 + mt * 16 + quad * 4 + r) * 136 + wc * 32 + nt * 16 + m] =
                        f2bf((acc[mt][nt][r] + bvv) * scale);
        }
        __syncthreads();
#pragma unroll
        for (int rep = 0; rep < 8; ++rep) {
            const int chunk = tid + rep * 512;      // 0..4095
            const int row = chunk >> 4;             // 0..255
            const int cc = (chunk & 15) * 8;        // 0..120
            const int colg = col0w + cc;
            const int h = colg >> 6, d = colg & 63;
            short8 v = *(const short8*)&EP[row * 136 + cc];
            *(short8*)&QK[((long)(b * HH + h) * SS + s0 + row) * DD + d] = v;
        }
    } else {
        // V -> [B,H,D,S]; EP transposed as [128][264]
#pragma unroll
        for (int nt = 0; nt < 2; ++nt) {
            const float bvv = bias[col0w + wc * 32 + nt * 16 + m];
#pragma unroll
            for (int mt = 0; mt < 8; ++mt) {
                short4v o;
                o.x = f2bf(acc[mt][nt][0] + bvv);
                o.y = f2bf(acc[mt][nt][1] + bvv);
                o.z = f2bf(acc[mt][nt][2] + bvv);
                o.w = f2bf(acc[mt][nt][3] + bvv);
                *(short4v*)&EP[(wc * 32 + nt * 16 + m) * 264 + wr * 128 + mt * 16 + quad * 4] = o;
            }
        }
        __syncthreads();
#pragma unroll
        for (int rep = 0; rep < 8; ++rep) {
            const int chunk = tid + rep * 512;      // 0..4095
            const int col = chunk >> 5;             // 0..127
            const int sc8 = (chunk & 31) * 8;       // 0..248
            const int colg = col0w + col;
            const int h = colg >> 6, d = colg & 63;
            short8 v = *(const short8*)&EP[col * 264 + sc8];
            *(short8*)&Vb[((long)(b * HH + h) * DD + d) * SS + s0 + sc8] = v;
        }
    }
}

// Output projection: Cb bf16 [M][E] @ WoT + bo -> fp32 d_out. 384 blocks,
// XCD chunk = 8 row-tiles x 6 cols.
__global__ __launch_bounds__(256)
void gemm_proj(const short* __restrict__ Cb, const short* __restrict__ WoT,
               const float* __restrict__ bo, float* __restrict__ out) {
    __shared__ short Al[128 * 64];
    __shared__ short Bl[128 * 64];
    const int tid = threadIdx.x, w = tid >> 6, lane = tid & 63;
    const int m = lane & 15, quad = lane >> 4;

    const int flat = blockIdx.x + 6 * blockIdx.y;       // 0..383
    const int id   = (flat & 7) * 48 + (flat >> 3);
    const int xcd  = id / 48;
    const int lcl  = id % 48;
    const int row0 = (xcd * 8 + (lcl & 7)) * 128;
    const int col0 = (lcl >> 3) * 128;

    GEMM_CORE(Cb, WoT, row0, col0)

#pragma unroll
    for (int nt = 0; nt < 4; ++nt) {
        const int colg = col0 + cn + nt * 16 + m;
        const float bvv = bo[colg];
#pragma unroll
        for (int mt = 0; mt < 4; ++mt)
#pragma unroll
            for (int r = 0; r < 4; ++r) {
                const int srow = row0 + rm + mt * 16 + quad * 4 + r;
                out[(long)srow * EE + colg] = acc[mt][nt][r] + bvv;
            }
    }
}

// ---------------------------------------------------------------------------
// Flash attention, bf16 MFMA 16x16x32 (round-1 version: gload_lds staging,
// double-buffered prefetch, setprio, XCD swizzle).
// ---------------------------------------------------------------------------
#define ATTN_STAGE(Kdst, Vdst, k0)                                            \
    do {                                                                      \
        _Pragma("unroll") for (int i = 0; i < 2; ++i) {                       \
            const int chunk = w * 128 + i * 64 + l;                           \
            const int r = chunk >> 3;                                         \
            const int cs = ((chunk & 7) ^ (r & 7)) << 3;                      \
            gload_lds16(&Kg[(long)((k0) + r) * DD + cs],                      \
                        (Kdst) + (w * 128 + i * 64) * 8);                     \
            gload_lds16(&Vg[(long)r * SS + (k0) + cs],                        \
                        (Vdst) + (w * 128 + i * 64) * 8);                     \
        }                                                                     \
    } while (0)

#define ATTN_COMPUTE(Kbuf, Vbuf)                                              \
    do {                                                                      \
        f32x4 sc[2][4];                                                       \
        __builtin_amdgcn_s_setprio(1);                                        \
        _Pragma("unroll") for (int nt = 0; nt < 4; ++nt) {                    \
            const short* kb = (Kbuf) + (nt * 16 + m) * 64;                    \
            short8 b0 = *(const short8*)&kb[(quad ^ (m & 7)) << 3];           \
            short8 b1 = *(const short8*)&kb[((4 + quad) ^ (m & 7)) << 3];     \
            _Pragma("unroll") for (int g = 0; g < 2; ++g) {                   \
                f32x4 a = (f32x4){0.f, 0.f, 0.f, 0.f};                        \
                a = __builtin_amdgcn_mfma_f32_16x16x32_bf16(aq[g][0], b0, a, 0, 0, 0); \
                a = __builtin_amdgcn_mfma_f32_16x16x32_bf16(aq[g][1], b1, a, 0, 0, 0); \
                sc[g][nt] = a;                                                \
            }                                                                 \
        }                                                                     \
        __builtin_amdgcn_s_setprio(0);                                        \
        _Pragma("unroll") for (int g = 0; g < 2; ++g)                         \
            _Pragma("unroll") for (int nt = 0; nt < 4; ++nt)                  \
                _Pragma("unroll") for (int r = 0; r < 4; ++r)                 \
                    sc[g][nt][r] = __builtin_amdgcn_exp2f(sc[g][nt][r]);      \
        short* Pw = Pl + w * 32 * 72;                                         \
        _Pragma("unroll") for (int g = 0; g < 2; ++g)                         \
            _Pragma("unroll") for (int nt = 0; nt < 4; ++nt)                  \
                _Pragma("unroll") for (int r = 0; r < 4; ++r)                 \
                    Pw[(g * 16 + quad * 4 + r) * 72 + nt * 16 + m] =          \
                        f2bf_fast(sc[g][nt][r]);                              \
        short8 ap[2][2];                                                      \
        _Pragma("unroll") for (int g = 0; g < 2; ++g) {                       \
            ap[g][0] = *(const short8*)(Pw + (g * 16 + m) * 72 + quad * 8);   \
            ap[g][1] = *(const short8*)(Pw + (g * 16 + m) * 72 + 32 + quad * 8); \
        }                                                                     \
        __builtin_amdgcn_s_setprio(1);                                        \
        _Pragma("unroll") for (int g = 0; g < 2; ++g) {                       \
            lacc[g] = __builtin_amdgcn_mfma_f32_16x16x32_bf16(ap[g][0], ones, lacc[g], 0, 0, 0); \
            lacc[g] = __builtin_amdgcn_mfma_f32_16x16x32_bf16(ap[g][1], ones, lacc[g], 0, 0, 0); \
        }                                                                     \
        _Pragma("unroll") for (int dt = 0; dt < 4; ++dt) {                    \
            const short* vb = (Vbuf) + (dt * 16 + m) * 64;                    \
            short8 b0 = *(const short8*)&vb[(quad ^ (m & 7)) << 3];           \
            short8 b1 = *(const short8*)&vb[((4 + quad) ^ (m & 7)) << 3];     \
            _Pragma("unroll") for (int g = 0; g < 2; ++g) {                   \
                O[g][dt] = __builtin_amdgcn_mfma_f32_16x16x32_bf16(ap[g][0], b0, O[g][dt], 0, 0, 0); \
                O[g][dt] = __builtin_amdgcn_mfma_f32_16x16x32_bf16(ap[g][1], b1, O[g][dt], 0, 0, 0); \
            }                                                                 \
        }                                                                     \
        __builtin_amdgcn_s_setprio(0);                                        \
    } while (0)

__global__ __launch_bounds__(256)
void attn_mfma(const short* __restrict__ Q,
               const short* __restrict__ K,
               const short* __restrict__ Vt,
               short* __restrict__ out) {
    __shared__ short K0l[64 * 64];
    __shared__ short K1l[64 * 64];
    __shared__ short V0l[64 * 64];
    __shared__ short V1l[64 * 64];
    __shared__ short Pl[4 * 32 * 72];

    const int tid  = threadIdx.x;
    const int w    = tid >> 6;
    const int l    = tid & 63;
    const int m    = l & 15;
    const int quad = l >> 4;

    const int flat = blockIdx.x + 8 * blockIdx.y + 96 * blockIdx.z;  // 0..767
    const int id   = (flat & 7) * 96 + (flat >> 3);
    const int qt   = id & 7;
    const int bh   = id >> 3;            // 0..95
    const int b    = bh / HH;
    const int h    = bh % HH;
    const int q0   = qt * 128;

    const short* Qg = Q  + (long)bh * SS * DD;
    const short* Kg = K  + (long)bh * SS * DD;
    const short* Vg = Vt + (long)bh * DD * SS;

    short8 aq[2][2];
#pragma unroll
    for (int g = 0; g < 2; ++g) {
        const int row = q0 + w * 32 + g * 16 + m;
        aq[g][0] = *(const short8*)(Qg + (long)row * DD + quad * 8);
        aq[g][1] = *(const short8*)(Qg + (long)row * DD + 32 + quad * 8);
    }

    short8 ones;
#pragma unroll
    for (int i = 0; i < 8; ++i) ones[i] = (short)0x3F80;

    f32x4 O[2][4], lacc[2];
#pragma unroll
    for (int g = 0; g < 2; ++g) {
        lacc[g] = (f32x4){0.f, 0.f, 0.f, 0.f};
#pragma unroll
        for (int dt = 0; dt < 4; ++dt) O[g][dt] = (f32x4){0.f, 0.f, 0.f, 0.f};
    }

    ATTN_STAGE(K0l, V0l, 0);
    __syncthreads();

#pragma unroll 1
    for (int kt2 = 0; kt2 < 8; ++kt2) {
        const int k0 = kt2 * 128;
        ATTN_STAGE(K1l, V1l, k0 + 64);
        ATTN_COMPUTE(K0l, V0l);
        __syncthreads();
        if (kt2 < 7) ATTN_STAGE(K0l, V0l, k0 + 128);
        ATTN_COMPUTE(K1l, V1l);
        __syncthreads();
    }

#pragma unroll
    for (int g = 0; g < 2; ++g)
#pragma unroll
        for (int r = 0; r < 4; ++r) {
            const float inv = 1.0f / lacc[g][r];
            const int qo = q0 + w * 32 + g * 16 + quad * 4 + r;
            short* orow = out + ((long)(b * SS + qo)) * EE + h * DD;
#pragma unroll
            for (int dt = 0; dt < 4; ++dt)
                orow[dt * 16 + m] = f2bf(O[g][dt][r] * inv);
        }
}

// ---------------------------------------------------------------------------
extern "C" void kernel_launch(void* const* d_in, const int* in_sizes, int n_in,
                              void* d_out, int out_size, void* d_ws, size_t ws_size,
                              hipStream_t stream) {
    const float* X  = (const float*)d_in[0];
    const float* Wq = (const float*)d_in[1];
    const float* bq = (const float*)d_in[2];
    const float* Wk = (const float*)d_in[3];
    const float* bk = (const float*)d_in[4];
    const float* Wv = (const float*)d_in[5];
    const float* bv = (const float*)d_in[6];
    const float* Wo = (const float*)d_in[7];
    const float* bo = (const float*)d_in[8];

    const long SEG = (long)BB * HH * SS * DD;     // 6,291,456 elements
    const long WSEG = (long)EE * EE;              // 589,824
    short* Xb = (short*)d_ws;                     // [M][E] bf16
    short* Wt = Xb + SEG;                         // [4][E][E] bf16, N-major
    short* Qb = Wt + 4 * WSEG;                    // [B,H,S,D] bf16, pre-scaled
    short* Kb = Qb + SEG;                         // [B,H,S,D] bf16
    short* Vb = Kb + SEG;                         // [B,H,D,S] bf16
    short* Cb = Vb + SEG;                         // [M][E] bf16 concat

    cast_x<<<dim3(MM * EE / 4 / 256), 256, 0, stream>>>(X, Xb);
    wcast_t<<<dim3(12, 12, 4), 256, 0, stream>>>(Wq, Wk, Wv, Wo, Wt);

    gemm_qkv<<<dim3(18, 32), 512, 0, stream>>>(Xb, Wt, bq, bk, bv, Qb, Kb, Vb);

    attn_mfma<<<dim3(SS / 128, HH, BB), 256, 0, stream>>>(Qb, Kb, Vb, Cb);

    gemm_proj<<<dim3(6, 64), 256, 0, stream>>>(Cb, Wt + 3 * WSEG, bo,
                                               (float*)d_out);
}

// Round 6
// 197.749 us; speedup vs baseline: 1.0607x; 1.0144x over previous
//
#include <hip/hip_runtime.h>
#include <math.h>

#define BB 8
#define SS 1024
#define EE 768
#define HH 12
#define DD 64
#define MM (BB*SS)   // 8192

typedef __attribute__((ext_vector_type(8))) short short8;   // 8 bf16 = 4 VGPRs
typedef __attribute__((ext_vector_type(4))) short short4v;  // 8 B
typedef __attribute__((ext_vector_type(4))) float f32x4;
typedef __attribute__((ext_vector_type(4))) int int4v;

// round-to-nearest-even fp32 -> bf16 bits (finite inputs only)
static __device__ __forceinline__ short f2bf(float x) {
    unsigned u = __float_as_uint(x);
    u += 0x7fffu + ((u >> 16) & 1u);
    return (short)(u >> 16);
}
// fast round-half-up (positive finite inputs; differs from RNE only on ties)
static __device__ __forceinline__ short f2bf_fast(float x) {
    return (short)((__float_as_uint(x) + 0x8000u) >> 16);
}

// packed fp32x2 -> bf16x2 (D.l = bf16(lo), D.h = bf16(hi))
static __device__ __forceinline__ int cvtpk_bf16(float lo, float hi) {
    int r;
    asm("v_cvt_pk_bf16_f32 %0, %1, %2" : "=v"(r) : "v"(lo), "v"(hi));
    return r;
}
static __device__ __forceinline__ short8 i4_to_s8(int4v v) {
    union { int4v i; short8 s; } u; u.i = v; return u.s;
}

// async global->LDS, 16B per lane; LDS dest = wave-uniform base + lane*16
static __device__ __forceinline__ void gload_lds16(const void* g, void* l) {
    __builtin_amdgcn_global_load_lds((__attribute__((address_space(1))) void*)g,
                                     (__attribute__((address_space(3))) void*)l,
                                     16, 0, 0);
}

#define BAR __builtin_amdgcn_s_barrier()
#define VMW(n) asm volatile("s_waitcnt vmcnt(" #n ")" ::: "memory")

// ---------------------------------------------------------------------------
// cast X fp32 -> bf16
// ---------------------------------------------------------------------------
__global__ __launch_bounds__(256)
void cast_x(const float* __restrict__ src, short* __restrict__ dst) {
    const long i = ((long)blockIdx.x * 256 + threadIdx.x) * 4;
    float4 v = *(const float4*)&src[i];
    short4v o;
    o.x = f2bf(v.x); o.y = f2bf(v.y); o.z = f2bf(v.z); o.w = f2bf(v.w);
    *(short4v*)&dst[i] = o;
}

// ---------------------------------------------------------------------------
// transpose+cast the 4 weight matrices [768][768] fp32 -> Wt[z][N][K] bf16
// ---------------------------------------------------------------------------
__global__ __launch_bounds__(256)
void wcast_t(const float* __restrict__ W0, const float* __restrict__ W1,
             const float* __restrict__ W2, const float* __restrict__ W3,
             short* __restrict__ Wt) {
    __shared__ short T[64][72];
    const int z = blockIdx.z;
    const float* sp = (z == 0) ? W0 : (z == 1) ? W1 : (z == 2) ? W2 : W3;
    short* dp = Wt + (long)z * EE * EE;
    const int i0 = blockIdx.y * 64;
    const int j0 = blockIdx.x * 64;
    const int tid = threadIdx.x;
#pragma unroll
    for (int rep = 0; rep < 4; ++rep) {
        const int r = (tid >> 4) + rep * 16;
        const int c = (tid & 15) * 4;
        float4 v = *(const float4*)&sp[(long)(i0 + r) * EE + j0 + c];
        T[c + 0][r] = f2bf(v.x);
        T[c + 1][r] = f2bf(v.y);
        T[c + 2][r] = f2bf(v.z);
        T[c + 3][r] = f2bf(v.w);
    }
    __syncthreads();
#pragma unroll
    for (int rep = 0; rep < 4; ++rep) {
        const int rr = (tid >> 4) + rep * 16;
        const int cc = (tid & 15) * 4;
        short4v o;
        o.x = T[rr][cc + 0]; o.y = T[rr][cc + 1];
        o.z = T[rr][cc + 2]; o.w = T[rr][cc + 3];
        *(short4v*)&dp[(long)(j0 + rr) * EE + i0 + cc] = o;
    }
}

// ---------------------------------------------------------------------------
// bf16 MFMA GEMM core (m97 structure) — still used by gemm_proj.
// ---------------------------------------------------------------------------
#define GEMM_CORE(Abase, Bbase, row0, col0)                                     \
    f32x4 acc[4][4];                                                            \
    _Pragma("unroll") for (int i = 0; i < 4; ++i)                               \
        _Pragma("unroll") for (int j = 0; j < 4; ++j)                           \
            acc[i][j] = (f32x4){0.f, 0.f, 0.f, 0.f};                            \
    const int rm = (w & 1) * 64, cn = (w >> 1) * 64;                            \
    for (int k0 = 0; k0 < EE; k0 += 64) {                                       \
        __syncthreads();                                                        \
        _Pragma("unroll") for (int i = 0; i < 4; ++i) {                         \
            const int chunk = w * 256 + i * 64 + lane;                          \
            const int r = chunk >> 3;                                          \
            const int cs = (((chunk & 7) ^ (r & 7)) << 3);                      \
            short* ldsA = Al + (w * 256 + i * 64) * 8;                          \
            short* ldsB = Bl + (w * 256 + i * 64) * 8;                          \
            gload_lds16(&Abase[(long)(row0 + r) * EE + k0 + cs], ldsA);         \
            gload_lds16(&Bbase[(long)(col0 + r) * EE + k0 + cs], ldsB);         \
        }                                                                       \
        __syncthreads();                                                        \
        _Pragma("unroll") for (int ks = 0; ks < 2; ++ks) {                      \
            short8 af[4], bf[4];                                                \
            _Pragma("unroll") for (int t = 0; t < 4; ++t)                       \
                af[t] = *(const short8*)&Al[(rm + t * 16 + m) * 64 +            \
                                            (((ks * 4 + quad) ^ (m & 7)) << 3)]; \
            _Pragma("unroll") for (int t = 0; t < 4; ++t)                       \
                bf[t] = *(const short8*)&Bl[(cn + t * 16 + m) * 64 +            \
                                            (((ks * 4 + quad) ^ (m & 7)) << 3)]; \
            _Pragma("unroll") for (int mt = 0; mt < 4; ++mt)                    \
                _Pragma("unroll") for (int nt = 0; nt < 4; ++nt)                \
                    acc[mt][nt] = __builtin_amdgcn_mfma_f32_16x16x32_bf16(      \
                        af[mt], bf[nt], acc[mt][nt], 0, 0, 0);                  \
        }                                                                       \
    }

// Q pre-scale: 1/sqrt(D) * log2(e)  (exp done as 2^x in attention)
#define QSCALE 0.1803368801111204f

// ---------------------------------------------------------------------------
// Fused QKV — 256x128 tile, BK=64, 512 thr / 8 waves (2M x 4N), per-wave
// C = 128x32 = acc[8][2]. 4-phase counted-vmcnt pipeline (T2+T4+T5).
// Grid 32x18 = 576 blocks. LDS 96 KiB. (round-3 version, verified)
// ---------------------------------------------------------------------------
#define STG1(Ld, Gbase, gr0, k0)                                              \
    do {                                                                      \
        const int r_ = tid >> 3;                                              \
        const int cs_ = ((tid & 7) ^ (r_ & 7)) << 3;                          \
        gload_lds16(&(Gbase)[(long)((gr0) + r_) * EE + (k0) + cs_],           \
                    (Ld) + w * 512);                                          \
    } while (0)

#define QKV_RDA(Ld, mb)                                                       \
    _Pragma("unroll") for (int t = 0; t < 4; ++t)                             \
        _Pragma("unroll") for (int ks = 0; ks < 2; ++ks)                      \
            af[t][ks] = *(const short8*)&(Ld)[(wr * 128 + ((mb) + t) * 16 + m) * 64 + \
                                              (((ks * 4 + quad) ^ (m & 7)) << 3)];

#define QKV_RDB(Ld)                                                           \
    _Pragma("unroll") for (int t = 0; t < 2; ++t)                             \
        _Pragma("unroll") for (int ks = 0; ks < 2; ++ks)                      \
            bf[t][ks] = *(const short8*)&(Ld)[(wc * 32 + t * 16 + m) * 64 +   \
                                              (((ks * 4 + quad) ^ (m & 7)) << 3)];

#define QKV_MF(mb)                                                            \
    __builtin_amdgcn_s_setprio(1);                                            \
    _Pragma("unroll") for (int mq = 0; mq < 4; ++mq)                          \
        _Pragma("unroll") for (int nq = 0; nq < 2; ++nq)                      \
            _Pragma("unroll") for (int ks = 0; ks < 2; ++ks)                  \
                acc[(mb) + mq][nq] = __builtin_amdgcn_mfma_f32_16x16x32_bf16( \
                    af[mq][ks], bf[nq][ks], acc[(mb) + mq][nq], 0, 0, 0);     \
    __builtin_amdgcn_s_setprio(0);

__global__ __launch_bounds__(512, 2)
void gemm_qkv(const short* __restrict__ Xb, const short* __restrict__ Wt,
              const float* __restrict__ bq, const float* __restrict__ bk,
              const float* __restrict__ bv,
              short* __restrict__ Qb, short* __restrict__ Kb,
              short* __restrict__ Vb) {
    __shared__ short SMEM[49152];            // 96 KiB
    short* const Ae = SMEM;                  // 256x64 bf16 even-tile A
    short* const Ao = SMEM + 16384;          // odd-tile A
    short* const Be = SMEM + 32768;          // 128x64 bf16 even-tile B
    short* const Bo = SMEM + 40960;          // odd-tile B

    const int tid = threadIdx.x;
    const int w = tid >> 6;
    const int m = tid & 15, quad = (tid & 63) >> 4;
    const int wr = w >> 2, wc = w & 3;       // 2M x 4N wave grid

    const int flat = blockIdx.x + 18 * blockIdx.y;      // 0..575
    const int id   = (flat & 7) * 72 + (flat >> 3);
    const int lcl  = id % 72;
    const int rt   = (id / 72) * 4 + (lcl & 3);         // 0..31
    const int ct   = lcl >> 2;                          // 0..17
    const int row0 = rt * 256;
    const int wsel = ct / 6;
    const int col0w = (ct % 6) * 128;
    const short* Wsel = Wt + (long)wsel * EE * EE;
    const float* bias = (wsel == 0) ? bq : (wsel == 1) ? bk : bv;

    f32x4 acc[8][2];
#pragma unroll
    for (int i = 0; i < 8; ++i)
#pragma unroll
        for (int j = 0; j < 2; ++j) acc[i][j] = (f32x4){0.f, 0.f, 0.f, 0.f};

    // ---- prologue: chain-compatible order, 10 loads ----
    STG1(Ae + 0,     Xb,   row0 + 0,    0);
    STG1(Ae + 8192,  Xb,   row0 + 128,  0);
    STG1(Be + 0,     Wsel, col0w + 0,   0);
    STG1(Be + 4096,  Wsel, col0w + 64,  0);
    STG1(Ae + 4096,  Xb,   row0 + 64,   0);
    STG1(Ae + 12288, Xb,   row0 + 192,  0);
    STG1(Bo + 0,     Wsel, col0w + 0,   64);
    STG1(Bo + 4096,  Wsel, col0w + 64,  64);
    STG1(Ao + 0,     Xb,   row0 + 0,    64);
    STG1(Ao + 8192,  Xb,   row0 + 128,  64);
    VMW(6);
    BAR;

#pragma unroll 1
    for (int it = 0; it < 6; ++it) {
        const int kO1 = (2 * it + 1) * 64;              // <= 704, always valid
        const int t2 = 2 * it + 2, t3 = 2 * it + 3;
        const int kE2 = (t2 < 12 ? t2 : 11) * 64;       // clamp: hot re-read
        const int kO3 = (t3 < 12 ? t3 : 11) * 64;
        short8 af[4][2], bf[2][2];
        // -- phase 1: even tile, M-half 0 --
        QKV_RDA(Ae, 0);
        QKV_RDB(Be);
        STG1(Ao + 4096,  Xb, row0 + 64,  kO1);
        STG1(Ao + 12288, Xb, row0 + 192, kO1);
        BAR;
        QKV_MF(0);
        VMW(6);
        BAR;
        // -- phase 2: even tile, M-half 1 (B-frags live in regs) --
        QKV_RDA(Ae, 4);
        STG1(Be + 0,     Wsel, col0w + 0,  kE2);
        STG1(Be + 4096,  Wsel, col0w + 64, kE2);
        STG1(Ae + 0,     Xb,   row0 + 0,   kE2);
        STG1(Ae + 8192,  Xb,   row0 + 128, kE2);
        BAR;
        QKV_MF(4);
        VMW(6);
        BAR;
        // -- phase 3: odd tile, M-half 0 --
        QKV_RDA(Ao, 0);
        QKV_RDB(Bo);
        STG1(Ae + 4096,  Xb, row0 + 64,  kE2);
        STG1(Ae + 12288, Xb, row0 + 192, kE2);
        BAR;
        QKV_MF(0);
        VMW(6);
        BAR;
        // -- phase 4: odd tile, M-half 1 --
        QKV_RDA(Ao, 4);
        STG1(Bo + 0,     Wsel, col0w + 0,  kO3);
        STG1(Bo + 4096,  Wsel, col0w + 64, kO3);
        STG1(Ao + 0,     Xb,   row0 + 0,   kO3);
        STG1(Ao + 8192,  Xb,   row0 + 128, kO3);
        BAR;
        QKV_MF(4);
        VMW(6);
        BAR;
    }

    // ---- epilogue ----
    VMW(0);
    __syncthreads();
    const int b = row0 >> 10, s0 = row0 & 1023;
    short* EP = SMEM;

    if (wsel < 2) {
        // Q/K -> [B,H,S,D]; EP as [256][136]
        const float scale = (wsel == 0) ? QSCALE : 1.0f;
        short* QK = (wsel == 0) ? Qb : Kb;
#pragma unroll
        for (int nt = 0; nt < 2; ++nt) {
            const float bvv = bias[col0w + wc * 32 + nt * 16 + m];
#pragma unroll
            for (int mt = 0; mt < 8; ++mt)
#pragma unroll
                for (int r = 0; r < 4; ++r)
                    EP[(wr * 128 + mt * 16 + quad * 4 + r) * 136 + wc * 32 + nt * 16 + m] =
                        f2bf((acc[mt][nt][r] + bvv) * scale);
        }
        __syncthreads();
#pragma unroll
        for (int rep = 0; rep < 8; ++rep) {
            const int chunk = tid + rep * 512;      // 0..4095
            const int row = chunk >> 4;             // 0..255
            const int cc = (chunk & 15) * 8;        // 0..120
            const int colg = col0w + cc;
            const int h = colg >> 6, d = colg & 63;
            short8 v = *(const short8*)&EP[row * 136 + cc];
            *(short8*)&QK[((long)(b * HH + h) * SS + s0 + row) * DD + d] = v;
        }
    } else {
        // V -> [B,H,D,S]; EP transposed as [128][264]
#pragma unroll
        for (int nt = 0; nt < 2; ++nt) {
            const float bvv = bias[col0w + wc * 32 + nt * 16 + m];
#pragma unroll
            for (int mt = 0; mt < 8; ++mt) {
                short4v o;
                o.x = f2bf(acc[mt][nt][0] + bvv);
                o.y = f2bf(acc[mt][nt][1] + bvv);
                o.z = f2bf(acc[mt][nt][2] + bvv);
                o.w = f2bf(acc[mt][nt][3] + bvv);
                *(short4v*)&EP[(wc * 32 + nt * 16 + m) * 264 + wr * 128 + mt * 16 + quad * 4] = o;
            }
        }
        __syncthreads();
#pragma unroll
        for (int rep = 0; rep < 8; ++rep) {
            const int chunk = tid + rep * 512;      // 0..4095
            const int col = chunk >> 5;             // 0..127
            const int sc8 = (chunk & 31) * 8;       // 0..248
            const int colg = col0w + col;
            const int h = colg >> 6, d = colg & 63;
            short8 v = *(const short8*)&EP[col * 264 + sc8];
            *(short8*)&Vb[((long)(b * HH + h) * DD + d) * SS + s0 + sc8] = v;
        }
    }
}

// Output projection: Cb bf16 [M][E] @ WoT + bo -> fp32 d_out. 384 blocks,
// XCD chunk = 8 row-tiles x 6 cols.
__global__ __launch_bounds__(256)
void gemm_proj(const short* __restrict__ Cb, const short* __restrict__ WoT,
               const float* __restrict__ bo, float* __restrict__ out) {
    __shared__ short Al[128 * 64];
    __shared__ short Bl[128 * 64];
    const int tid = threadIdx.x, w = tid >> 6, lane = tid & 63;
    const int m = lane & 15, quad = lane >> 4;

    const int flat = blockIdx.x + 6 * blockIdx.y;       // 0..383
    const int id   = (flat & 7) * 48 + (flat >> 3);
    const int xcd  = id / 48;
    const int lcl  = id % 48;
    const int row0 = (xcd * 8 + (lcl & 7)) * 128;
    const int col0 = (lcl >> 3) * 128;

    GEMM_CORE(Cb, WoT, row0, col0)

#pragma unroll
    for (int nt = 0; nt < 4; ++nt) {
        const int colg = col0 + cn + nt * 16 + m;
        const float bvv = bo[colg];
#pragma unroll
        for (int mt = 0; mt < 4; ++mt)
#pragma unroll
            for (int r = 0; r < 4; ++r) {
                const int srow = row0 + rm + mt * 16 + quad * 4 + r;
                out[(long)srow * EE + colg] = acc[mt][nt][r] + bvv;
            }
    }
}

// ---------------------------------------------------------------------------
// Flash attention, bf16 MFMA 16x16x32. SWAPPED QK^T + in-register P.
//
// S^T = mfma(A=K_frag, B=Q_frag): operand swap is free (A-frag and B-frag
// addressing are identical); lane (m,quad) then holds P[q=g*16+m][key =
// nt*16+quad*4+r] — its OWN q-row. PV contraction order is arbitrary if A
// and B use the same permutation sigma: slot(hf,quad,j) <-> key =
// (2hf+(j>>2))*16 + quad*4 + (j&3). Under sigma each lane's held keys are
// EXACTLY its PV A-frag slots: A-frags built by 16 v_cvt_pk_bf16_f32, zero
// LDS, zero cross-lane. V B-frag reads become per-register two 8B chunks
// (ds_read_b64 x2, even 2-per-bank). Row-sum via ones-MFMA, O layout,
// epilogue all unchanged. P LDS buffer deleted (51200 -> 32768 B).
// ---------------------------------------------------------------------------
#define ATTN_STAGE(Kdst, Vdst, k0)                                            \
    do {                                                                      \
        _Pragma("unroll") for (int i = 0; i < 2; ++i) {                       \
            const int chunk = w * 128 + i * 64 + l;                           \
            const int r = chunk >> 3;                                         \
            const int cs = ((chunk & 7) ^ (r & 7)) << 3;                      \
            gload_lds16(&Kg[(long)((k0) + r) * DD + cs],                      \
                        (Kdst) + (w * 128 + i * 64) * 8);                     \
            gload_lds16(&Vg[(long)r * SS + (k0) + cs],                        \
                        (Vdst) + (w * 128 + i * 64) * 8);                     \
        }                                                                     \
    } while (0)

#define ATTN_COMPUTE(Kbuf, Vbuf)                                              \
    do {                                                                      \
        f32x4 sc[2][4];                                                       \
        __builtin_amdgcn_s_setprio(1);                                        \
        _Pragma("unroll") for (int nt = 0; nt < 4; ++nt) {                    \
            const short* kb = (Kbuf) + (nt * 16 + m) * 64;                    \
            short8 a0 = *(const short8*)&kb[(quad ^ (m & 7)) << 3];           \
            short8 a1 = *(const short8*)&kb[((4 + quad) ^ (m & 7)) << 3];     \
            _Pragma("unroll") for (int g = 0; g < 2; ++g) {                   \
                f32x4 a = (f32x4){0.f, 0.f, 0.f, 0.f};                        \
                a = __builtin_amdgcn_mfma_f32_16x16x32_bf16(a0, aq[g][0], a, 0, 0, 0); \
                a = __builtin_amdgcn_mfma_f32_16x16x32_bf16(a1, aq[g][1], a, 0, 0, 0); \
                sc[g][nt] = a;                                                \
            }                                                                 \
        }                                                                     \
        __builtin_amdgcn_s_setprio(0);                                        \
        _Pragma("unroll") for (int g = 0; g < 2; ++g)                         \
            _Pragma("unroll") for (int nt = 0; nt < 4; ++nt)                  \
                _Pragma("unroll") for (int r = 0; r < 4; ++r)                 \
                    sc[g][nt][r] = __builtin_amdgcn_exp2f(sc[g][nt][r]);      \
        short8 ap[2][2];                                                      \
        _Pragma("unroll") for (int g = 0; g < 2; ++g)                         \
            _Pragma("unroll") for (int hf = 0; hf < 2; ++hf) {                \
                int4v wv;                                                     \
                wv.x = cvtpk_bf16(sc[g][2 * hf + 0][0], sc[g][2 * hf + 0][1]); \
                wv.y = cvtpk_bf16(sc[g][2 * hf + 0][2], sc[g][2 * hf + 0][3]); \
                wv.z = cvtpk_bf16(sc[g][2 * hf + 1][0], sc[g][2 * hf + 1][1]); \
                wv.w = cvtpk_bf16(sc[g][2 * hf + 1][2], sc[g][2 * hf + 1][3]); \
                ap[g][hf] = i4_to_s8(wv);                                     \
            }                                                                 \
        __builtin_amdgcn_s_setprio(1);                                        \
        _Pragma("unroll") for (int g = 0; g < 2; ++g) {                       \
            lacc[g] = __builtin_amdgcn_mfma_f32_16x16x32_bf16(ap[g][0], ones, lacc[g], 0, 0, 0); \
            lacc[g] = __builtin_amdgcn_mfma_f32_16x16x32_bf16(ap[g][1], ones, lacc[g], 0, 0, 0); \
        }                                                                     \
        const int rsw = m & 7, hb = (quad & 1) * 4;                           \
        _Pragma("unroll") for (int dt = 0; dt < 4; ++dt) {                    \
            const short* vb = (Vbuf) + (dt * 16 + m) * 64;                    \
            short4v l0 = *(const short4v*)&vb[((((quad >> 1) + 0) ^ rsw) << 3) + hb]; \
            short4v h0 = *(const short4v*)&vb[((((quad >> 1) + 2) ^ rsw) << 3) + hb]; \
            short4v l1 = *(const short4v*)&vb[((((quad >> 1) + 4) ^ rsw) << 3) + hb]; \
            short4v h1 = *(const short4v*)&vb[((((quad >> 1) + 6) ^ rsw) << 3) + hb]; \
            short8 b0 = __builtin_shufflevector(l0, h0, 0, 1, 2, 3, 4, 5, 6, 7); \
            short8 b1 = __builtin_shufflevector(l1, h1, 0, 1, 2, 3, 4, 5, 6, 7); \
            _Pragma("unroll") for (int g = 0; g < 2; ++g) {                   \
                O[g][dt] = __builtin_amdgcn_mfma_f32_16x16x32_bf16(ap[g][0], b0, O[g][dt], 0, 0, 0); \
                O[g][dt] = __builtin_amdgcn_mfma_f32_16x16x32_bf16(ap[g][1], b1, O[g][dt], 0, 0, 0); \
            }                                                                 \
        }                                                                     \
        __builtin_amdgcn_s_setprio(0);                                        \
    } while (0)

__global__ __launch_bounds__(256)
void attn_mfma(const short* __restrict__ Q,
               const short* __restrict__ K,
               const short* __restrict__ Vt,
               short* __restrict__ out) {
    __shared__ short K0l[64 * 64];       // 8192 B each; double-buffered
    __shared__ short K1l[64 * 64];
    __shared__ short V0l[64 * 64];
    __shared__ short V1l[64 * 64];

    const int tid  = threadIdx.x;
    const int w    = tid >> 6;
    const int l    = tid & 63;
    const int m    = l & 15;
    const int quad = l >> 4;

    const int flat = blockIdx.x + 8 * blockIdx.y + 96 * blockIdx.z;  // 0..767
    const int id   = (flat & 7) * 96 + (flat >> 3);
    const int qt   = id & 7;
    const int bh   = id >> 3;            // 0..95
    const int b    = bh / HH;
    const int h    = bh % HH;
    const int q0   = qt * 128;

    const short* Qg = Q  + (long)bh * SS * DD;
    const short* Kg = K  + (long)bh * SS * DD;
    const short* Vg = Vt + (long)bh * DD * SS;

    // Q B-fragments (swapped QK): lane m = q, regs = d — same addressing
    short8 aq[2][2];
#pragma unroll
    for (int g = 0; g < 2; ++g) {
        const int row = q0 + w * 32 + g * 16 + m;
        aq[g][0] = *(const short8*)(Qg + (long)row * DD + quad * 8);
        aq[g][1] = *(const short8*)(Qg + (long)row * DD + 32 + quad * 8);
    }

    short8 ones;
#pragma unroll
    for (int i = 0; i < 8; ++i) ones[i] = (short)0x3F80;

    f32x4 O[2][4], lacc[2];
#pragma unroll
    for (int g = 0; g < 2; ++g) {
        lacc[g] = (f32x4){0.f, 0.f, 0.f, 0.f};
#pragma unroll
        for (int dt = 0; dt < 4; ++dt) O[g][dt] = (f32x4){0.f, 0.f, 0.f, 0.f};
    }

    ATTN_STAGE(K0l, V0l, 0);
    __syncthreads();

#pragma unroll 1
    for (int kt2 = 0; kt2 < 8; ++kt2) {
        const int k0 = kt2 * 128;
        ATTN_STAGE(K1l, V1l, k0 + 64);
        ATTN_COMPUTE(K0l, V0l);
        __syncthreads();
        if (kt2 < 7) ATTN_STAGE(K0l, V0l, k0 + 128);
        ATTN_COMPUTE(K1l, V1l);
        __syncthreads();
    }

#pragma unroll
    for (int g = 0; g < 2; ++g)
#pragma unroll
        for (int r = 0; r < 4; ++r) {
            const float inv = 1.0f / lacc[g][r];
            const int qo = q0 + w * 32 + g * 16 + quad * 4 + r;
            short* orow = out + ((long)(b * SS + qo)) * EE + h * DD;
#pragma unroll
            for (int dt = 0; dt < 4; ++dt)
                orow[dt * 16 + m] = f2bf(O[g][dt][r] * inv);
        }
}

// ---------------------------------------------------------------------------
extern "C" void kernel_launch(void* const* d_in, const int* in_sizes, int n_in,
                              void* d_out, int out_size, void* d_ws, size_t ws_size,
                              hipStream_t stream) {
    const float* X  = (const float*)d_in[0];
    const float* Wq = (const float*)d_in[1];
    const float* bq = (const float*)d_in[2];
    const float* Wk = (const float*)d_in[3];
    const float* bk = (const float*)d_in[4];
    const float* Wv = (const float*)d_in[5];
    const float* bv = (const float*)d_in[6];
    const float* Wo = (const float*)d_in[7];
    const float* bo = (const float*)d_in[8];

    const long SEG = (long)BB * HH * SS * DD;     // 6,291,456 elements
    const long WSEG = (long)EE * EE;              // 589,824
    short* Xb = (short*)d_ws;                     // [M][E] bf16
    short* Wt = Xb + SEG;                         // [4][E][E] bf16, N-major
    short* Qb = Wt + 4 * WSEG;                    // [B,H,S,D] bf16, pre-scaled
    short* Kb = Qb + SEG;                         // [B,H,S,D] bf16
    short* Vb = Kb + SEG;                         // [B,H,D,S] bf16
    short* Cb = Vb + SEG;                         // [M][E] bf16 concat

    cast_x<<<dim3(MM * EE / 4 / 256), 256, 0, stream>>>(X, Xb);
    wcast_t<<<dim3(12, 12, 4), 256, 0, stream>>>(Wq, Wk, Wv, Wo, Wt);

    gemm_qkv<<<dim3(18, 32), 512, 0, stream>>>(Xb, Wt, bq, bk, bv, Qb, Kb, Vb);

    attn_mfma<<<dim3(SS / 128, HH, BB), 256, 0, stream>>>(Qb, Kb, Vb, Cb);

    gemm_proj<<<dim3(6, 64), 256, 0, stream>>>(Cb, Wt + 3 * WSEG, bo,
                                               (float*)d_out);
}